// Round 5
// baseline (769.217 us; speedup 1.0000x reference)
//
#include <hip/hip_runtime.h>
#include <hip/hip_bf16.h>

#define T_SEQ 1024
#define BATCH 512
#define INPUT 64
#define HID   128

typedef __attribute__((ext_vector_type(8))) short bf16x8;
typedef __attribute__((ext_vector_type(4))) short s16x4;
typedef __attribute__((ext_vector_type(4))) float f32x4;
typedef __attribute__((ext_vector_type(2))) unsigned int u32x2;

#define MFMA __builtin_amdgcn_mfma_f32_16x16x32_bf16

__device__ __forceinline__ short f2bf(float f) {
    union { float f; unsigned u; } v; v.f = f;
    unsigned r = (v.u + 0x7FFFu + ((v.u >> 16) & 1u)) >> 16;
    return (short)r;
}

// packed RNE f32x2 -> bf16x2
__device__ __forceinline__ unsigned cvtpk_bf16(float lo, float hi) {
    unsigned r;
    asm("v_cvt_pk_bf16_f32 %0, %1, %2" : "=v"(r) : "v"(lo), "v"(hi));
    return r;
}

// tanh(x) = 1 - 2/(exp(2x)+1); inf-safe
__device__ __forceinline__ float fast_tanh(float s) {
    float e = __expf(2.0f * s);
    return 1.0f - 2.0f * __builtin_amdgcn_rcpf(e + 1.0f);
}

__device__ __forceinline__ float hsig(float v) {
    return __builtin_amdgcn_fmed3f(v * 0.16666666666666666f + 0.5f, 0.0f, 1.0f);
}

// Barrier draining ONLY lgkmcnt (LDS). Global x-prefetch loads stay in flight.
__device__ __forceinline__ void wg_barrier_lds() {
    asm volatile("s_waitcnt lgkmcnt(0)" ::: "memory");
    __builtin_amdgcn_s_barrier();
    asm volatile("" ::: "memory");
}

// ---------------- prep: f32 -> bf16 bulk convert (W_map only) ----------------
__global__ __launch_bounds__(256) void cvt_kernel(const float* __restrict__ in,
                                                  short* __restrict__ out, int n4) {
    int i = blockIdx.x * 256 + threadIdx.x;
    if (i >= n4) return;
    f32x4 v = ((const f32x4*)in)[i];
    s16x4 o;
    #pragma unroll
    for (int j = 0; j < 4; ++j) o[j] = f2bf(v[j]);
    ((s16x4*)out)[i] = o;
}

// ---------------- Stage 1: recurrence (R2 structure: 2-group pipelined) ----------------
// 32 blocks x 512 threads. Block: 16 batches. Best-measured structure (449.8us).
// Step time is serial-chain-bound (R0-R4: invariant ~1090cyc vs issue load), so:
// x is consumed as f32 DIRECTLY (no cvt prekernel): shadow issues raw f32 loads
// into registers, converts 2 group-intervals later (f2bf = free shadow VALU).
// Group A = waves 0..3 owns even t; group B = waves 4..7 odd t. Critical interval:
// read h(t-1), 8 h-MFMAs, tanh, pack, write. Shadow interval: gate(t-1) MFMAs +
// agg + accx(t+1) + x-load issue.
__global__ __launch_bounds__(512, 1) void rnn_kernel(
    const float* __restrict__ xf_,
    const float* __restrict__ W_ih, const float* __restrict__ b_ih,
    const float* __restrict__ W_hh, const float* __restrict__ b_hh,
    const float* __restrict__ W_gate, const float* __restrict__ b_gate,
    float* __restrict__ agg_out)
{
    __shared__ __align__(16) short sh[2][16][136];

    const int tid  = threadIdx.x;
    const int wave = tid >> 6, lane = tid & 63;
    const int q = lane >> 4, l15 = lane & 15;
    const int b0 = blockIdx.x * 16;
    const int group = wave >> 2;          // 0: even steps, 1: odd steps
    const int gw = wave & 3;              // hidden rows [32*gw, 32*gw+32)
    const int R0 = 32 * gw, R1 = R0 + 16;

    // ---- one-time: weight A-frags (lane: W[row = Rt + l15][k = 32f + q*8 + j]) ----
    bf16x8 wih[2][2], whh[2][4], wgf[2][4];
    #pragma unroll
    for (int tile = 0; tile < 2; ++tile) {
        const int row = (tile ? R1 : R0) + l15;
        #pragma unroll
        for (int f = 0; f < 2; ++f) {
            const float* p = W_ih + row * INPUT + f * 32 + q * 8;
            bf16x8 v;
            #pragma unroll
            for (int j = 0; j < 8; ++j) v[j] = f2bf(p[j]);
            wih[tile][f] = v;
        }
        #pragma unroll
        for (int f = 0; f < 4; ++f) {
            const float* p = W_hh + row * HID + f * 32 + q * 8;
            bf16x8 v;
            #pragma unroll
            for (int j = 0; j < 8; ++j) v[j] = f2bf(p[j]);
            whh[tile][f] = v;
        }
        #pragma unroll
        for (int f = 0; f < 4; ++f) {
            const float* p = W_gate + row * HID + f * 32 + q * 8;
            bf16x8 v;
            #pragma unroll
            for (int j = 0; j < 8; ++j) v[j] = f2bf(p[j]);
            wgf[tile][f] = v;
        }
    }

    // ---- biases in C^T layout: row = Rt + q*4 + r ----
    f32x4 bias1[2], biasg[2], zero4;
    #pragma unroll
    for (int tile = 0; tile < 2; ++tile) {
        const int rbase = (tile ? R1 : R0) + q * 4;
        #pragma unroll
        for (int r = 0; r < 4; ++r) {
            bias1[tile][r] = b_ih[rbase + r] + b_hh[rbase + r];
            biasg[tile][r] = b_gate[rbase + r];
        }
    }
    #pragma unroll
    for (int r = 0; r < 4; ++r) zero4[r] = 0.0f;

    f32x4 agg0 = zero4, agg1 = zero4;
    f32x4 hpA = zero4, hpB = zero4;       // own h(s) values (f32, C^T layout)
    f32x4 accx0, accx1;                   // x-part for next own critical step
    // raw f32 x double-buffer (converted at consumption, 2 group-intervals later)
    f32x4 P0, P1, P2, P3, Q0, Q1, Q2, Q3;

    const float* xf_lane = xf_ + ((long)(b0 + l15) * T_SEQ) * INPUT + q * 8;

    // step t: h(t) = tanh(W_hh h(t-1) + accx(t)); write sh[t&1]
    auto critical = [&](int t) {
        const int rb = (t & 1) ^ 1, wb = t & 1;
        bf16x8 hf0 = *(const bf16x8*)&sh[rb][l15][q * 8];
        bf16x8 hf1 = *(const bf16x8*)&sh[rb][l15][32 + q * 8];
        bf16x8 hf2 = *(const bf16x8*)&sh[rb][l15][64 + q * 8];
        bf16x8 hf3 = *(const bf16x8*)&sh[rb][l15][96 + q * 8];
        f32x4 a0 = MFMA(whh[0][0], hf0, accx0, 0, 0, 0);
        f32x4 c0 = MFMA(whh[0][2], hf2, zero4, 0, 0, 0);
        f32x4 a1 = MFMA(whh[1][0], hf0, accx1, 0, 0, 0);
        f32x4 c1 = MFMA(whh[1][2], hf2, zero4, 0, 0, 0);
        a0 = MFMA(whh[0][1], hf1, a0, 0, 0, 0);
        c0 = MFMA(whh[0][3], hf3, c0, 0, 0, 0);
        a1 = MFMA(whh[1][1], hf1, a1, 0, 0, 0);
        c1 = MFMA(whh[1][3], hf3, c1, 0, 0, 0);
        hpA[0] = fast_tanh(a0[0] + c0[0]);
        hpA[1] = fast_tanh(a0[1] + c0[1]);
        hpA[2] = fast_tanh(a0[2] + c0[2]);
        hpA[3] = fast_tanh(a0[3] + c0[3]);
        hpB[0] = fast_tanh(a1[0] + c1[0]);
        hpB[1] = fast_tanh(a1[1] + c1[1]);
        hpB[2] = fast_tanh(a1[2] + c1[2]);
        hpB[3] = fast_tanh(a1[3] + c1[3]);
        u32x2 p0, p1;
        p0[0] = cvtpk_bf16(hpA[0], hpA[1]); p0[1] = cvtpk_bf16(hpA[2], hpA[3]);
        p1[0] = cvtpk_bf16(hpB[0], hpB[1]); p1[1] = cvtpk_bf16(hpB[2], hpB[3]);
        *(u32x2*)&sh[wb][l15][R0 + q * 4] = p0;
        *(u32x2*)&sh[wb][l15][R1 + q * 4] = p1;
    };

    // shadow t: gate(t-1) + agg; accx(t+1) from raw buffer (loaded 2 intervals ago);
    // reload buffer with x(t+5).
    auto shadow = [&](int t, f32x4& r0, f32x4& r1, f32x4& r2, f32x4& r3) {
        const int rb = (t & 1) ^ 1;
        bf16x8 gf0 = *(const bf16x8*)&sh[rb][l15][q * 8];
        bf16x8 gf1 = *(const bf16x8*)&sh[rb][l15][32 + q * 8];
        bf16x8 gf2 = *(const bf16x8*)&sh[rb][l15][64 + q * 8];
        bf16x8 gf3 = *(const bf16x8*)&sh[rb][l15][96 + q * 8];
        // convert raw x(t+1) -> frags (loads long since landed)
        bf16x8 fa, fb;
        #pragma unroll
        for (int j = 0; j < 4; ++j) {
            fa[j] = f2bf(r0[j]); fa[4 + j] = f2bf(r1[j]);
            fb[j] = f2bf(r2[j]); fb[4 + j] = f2bf(r3[j]);
        }
        accx0 = MFMA(wih[0][0], fa, bias1[0], 0, 0, 0);
        accx1 = MFMA(wih[1][0], fa, bias1[1], 0, 0, 0);
        accx0 = MFMA(wih[0][1], fb, accx0, 0, 0, 0);
        accx1 = MFMA(wih[1][1], fb, accx1, 0, 0, 0);
        // issue raw loads x(t+5) into this buffer (consumed at shadow(t+4))
        int tt = t + 5; if (tt > T_SEQ - 1) tt = T_SEQ - 1;
        {
            const float* p = xf_lane + (long)tt * INPUT;
            r0 = *(const f32x4*)p;        r1 = *(const f32x4*)(p + 4);
            r2 = *(const f32x4*)(p + 32); r3 = *(const f32x4*)(p + 36);
        }
        f32x4 g0 = MFMA(wgf[0][0], gf0, biasg[0], 0, 0, 0);
        f32x4 e0 = MFMA(wgf[0][2], gf2, zero4, 0, 0, 0);
        f32x4 g1 = MFMA(wgf[1][0], gf0, biasg[1], 0, 0, 0);
        f32x4 e1 = MFMA(wgf[1][2], gf2, zero4, 0, 0, 0);
        g0 = MFMA(wgf[0][1], gf1, g0, 0, 0, 0);
        e0 = MFMA(wgf[0][3], gf3, e0, 0, 0, 0);
        g1 = MFMA(wgf[1][1], gf1, g1, 0, 0, 0);
        e1 = MFMA(wgf[1][3], gf3, e1, 0, 0, 0);
        #pragma unroll
        for (int r = 0; r < 4; ++r) {
            agg0[r] += hpA[r] * hsig(g0[r] + e0[r]);
            agg1[r] += hpB[r] * hsig(g1[r] + e1[r]);
        }
    };

    // ---- prologue ----
    {
        // accx(group) via immediate load+convert
        const float* p = xf_lane + (long)group * INPUT;
        f32x4 a0 = *(const f32x4*)p,        a1 = *(const f32x4*)(p + 4);
        f32x4 a2 = *(const f32x4*)(p + 32), a3 = *(const f32x4*)(p + 36);
        bf16x8 ta, tb;
        #pragma unroll
        for (int j = 0; j < 4; ++j) {
            ta[j] = f2bf(a0[j]); ta[4 + j] = f2bf(a1[j]);
            tb[j] = f2bf(a2[j]); tb[4 + j] = f2bf(a3[j]);
        }
        accx0 = MFMA(wih[0][0], ta, bias1[0], 0, 0, 0);
        accx1 = MFMA(wih[1][0], ta, bias1[1], 0, 0, 0);
        accx0 = MFMA(wih[0][1], tb, accx0, 0, 0, 0);
        accx1 = MFMA(wih[1][1], tb, accx1, 0, 0, 0);
        if (group == 0) {
            // h(0) = tanh(accx(0)); write buf[0]
            hpA[0] = fast_tanh(accx0[0]); hpA[1] = fast_tanh(accx0[1]);
            hpA[2] = fast_tanh(accx0[2]); hpA[3] = fast_tanh(accx0[3]);
            hpB[0] = fast_tanh(accx1[0]); hpB[1] = fast_tanh(accx1[1]);
            hpB[2] = fast_tanh(accx1[2]); hpB[3] = fast_tanh(accx1[3]);
            u32x2 p0, p1;
            p0[0] = cvtpk_bf16(hpA[0], hpA[1]); p0[1] = cvtpk_bf16(hpA[2], hpA[3]);
            p1[0] = cvtpk_bf16(hpB[0], hpB[1]); p1[1] = cvtpk_bf16(hpB[2], hpB[3]);
            *(u32x2*)&sh[0][l15][R0 + q * 4] = p0;
            *(u32x2*)&sh[0][l15][R1 + q * 4] = p1;
        }
        // raw prefetch: A: x(2)->P, x(4)->Q ; B: x(3)->P, x(5)->Q
        const float* pp = xf_lane + (long)(group ? 3 : 2) * INPUT;
        P0 = *(const f32x4*)pp;        P1 = *(const f32x4*)(pp + 4);
        P2 = *(const f32x4*)(pp + 32); P3 = *(const f32x4*)(pp + 36);
        const float* pq = xf_lane + (long)(group ? 5 : 4) * INPUT;
        Q0 = *(const f32x4*)pq;        Q1 = *(const f32x4*)(pq + 4);
        Q2 = *(const f32x4*)(pq + 32); Q3 = *(const f32x4*)(pq + 36);
    }
    wg_barrier_lds();

    // ---- main loop ----
    if (group == 0) {
        // shadows at odd t (P,Q,P,Q...), criticals at even t
        shadow(1, P0, P1, P2, P3);   wg_barrier_lds();
        critical(2);                 wg_barrier_lds();
        for (int i = 0; i < 255; ++i) {
            shadow(4 * i + 3, Q0, Q1, Q2, Q3); wg_barrier_lds();
            critical(4 * i + 4);               wg_barrier_lds();
            shadow(4 * i + 5, P0, P1, P2, P3); wg_barrier_lds();
            critical(4 * i + 6);               wg_barrier_lds();
        }
        shadow(1023, Q0, Q1, Q2, Q3); wg_barrier_lds();
    } else {
        // criticals at odd t, shadows at even t (P,Q,P,Q...)
        critical(1);                 wg_barrier_lds();
        shadow(2, P0, P1, P2, P3);   wg_barrier_lds();
        for (int i = 0; i < 255; ++i) {
            critical(4 * i + 3);               wg_barrier_lds();
            shadow(4 * i + 4, Q0, Q1, Q2, Q3); wg_barrier_lds();
            critical(4 * i + 5);               wg_barrier_lds();
            shadow(4 * i + 6, P0, P1, P2, P3); wg_barrier_lds();
        }
        critical(1023); wg_barrier_lds();
    }

    // ---- epilogue ----
    // B owns h(1023) (in sh[1]): compute its last gate term.
    if (group == 1) {
        bf16x8 gf0 = *(const bf16x8*)&sh[1][l15][q * 8];
        bf16x8 gf1 = *(const bf16x8*)&sh[1][l15][32 + q * 8];
        bf16x8 gf2 = *(const bf16x8*)&sh[1][l15][64 + q * 8];
        bf16x8 gf3 = *(const bf16x8*)&sh[1][l15][96 + q * 8];
        f32x4 g0 = MFMA(wgf[0][0], gf0, biasg[0], 0, 0, 0);
        f32x4 e0 = MFMA(wgf[0][2], gf2, zero4, 0, 0, 0);
        f32x4 g1 = MFMA(wgf[1][0], gf0, biasg[1], 0, 0, 0);
        f32x4 e1 = MFMA(wgf[1][2], gf2, zero4, 0, 0, 0);
        g0 = MFMA(wgf[0][1], gf1, g0, 0, 0, 0);
        e0 = MFMA(wgf[0][3], gf3, e0, 0, 0, 0);
        g1 = MFMA(wgf[1][1], gf1, g1, 0, 0, 0);
        e1 = MFMA(wgf[1][3], gf3, e1, 0, 0, 0);
        #pragma unroll
        for (int r = 0; r < 4; ++r) {
            agg0[r] += hpA[r] * hsig(g0[r] + e0[r]);
            agg1[r] += hpB[r] * hsig(g1[r] + e1[r]);
        }
    }
    wg_barrier_lds();                      // B's gf reads done before A overwrites LDS

    float* aggf = (float*)&sh[0][0][0];    // reuse as float[16][128]
    if (group == 0) {
        *(f32x4*)&aggf[l15 * HID + R0 + q * 4] = agg0;
        *(f32x4*)&aggf[l15 * HID + R1 + q * 4] = agg1;
    }
    wg_barrier_lds();
    if (group == 1) {
        const float s = 1.0f / (float)T_SEQ;
        f32x4 t0 = *(const f32x4*)&aggf[l15 * HID + R0 + q * 4];
        f32x4 t1 = *(const f32x4*)&aggf[l15 * HID + R1 + q * 4];
        #pragma unroll
        for (int r = 0; r < 4; ++r) { t0[r] = (t0[r] + agg0[r]) * s; t1[r] = (t1[r] + agg1[r]) * s; }
        *(f32x4*)&agg_out[(long)(b0 + l15) * HID + R0 + q * 4] = t0;
        *(f32x4*)&agg_out[(long)(b0 + l15) * HID + R1 + q * 4] = t1;
    }
}

// ---------------- Stage 2: mapped = agg @ W_map^T + b_map, FUSED pool+gate ----------------
// Block (mb, nb): batches mb*16..+16, cols nb*128..+128. col = c*1024 + h*32 + w
// with c = nb>>3, h = 4*(nb&7) + wave, w = tn*16 + l15: the block covers exactly
// one pool-window row (ph = nb&7, pw = 0..7) -> 4x4 pooling is block-local.
// Reduce: shfl over 4-lane w-groups, per-wave LDS partials over h, then
// gate = hsig(sum/16) and multiply before the single store (pool kernel deleted).
template<bool PRE>
__global__ __launch_bounds__(256) void map_kernel(
    const float* __restrict__ agg, const float* __restrict__ Wf,
    const short* __restrict__ Wb, const float* __restrict__ b_map,
    float* __restrict__ out)
{
    __shared__ float sh_pool[4][16][8];
    __shared__ float sh_gate[16][8];

    const int tid  = threadIdx.x;
    const int wave = tid >> 6, lane = tid & 63;
    const int q = lane >> 4, l15 = lane & 15;
    const int mb = blockIdx.x & 31;
    const int nb = blockIdx.x >> 5;
    const int b0 = mb * 16;
    const int n0 = nb * 128 + wave * 32;

    bf16x8 af[4];
    #pragma unroll
    for (int kb = 0; kb < 4; ++kb) {
        const float* p = agg + (b0 + l15) * HID + kb * 32 + q * 8;
        bf16x8 f;
        #pragma unroll
        for (int j = 0; j < 8; ++j) f[j] = f2bf(p[j]);
        af[kb] = f;
    }
    f32x4 cc[2];
    #pragma unroll
    for (int tn = 0; tn < 2; ++tn) {
        int nn = n0 + tn * 16 + l15;
        float bias = b_map[nn];
        f32x4 c;
        #pragma unroll
        for (int r = 0; r < 4; ++r) c[r] = bias;
        #pragma unroll
        for (int kb = 0; kb < 4; ++kb) {
            bf16x8 f;
            if (PRE) {
                f = *(const bf16x8*)(Wb + (long)nn * HID + kb * 32 + q * 8);
            } else {
                const float* p = Wf + (long)nn * HID + kb * 32 + q * 8;
                #pragma unroll
                for (int j = 0; j < 8; ++j) f[j] = f2bf(p[j]);
            }
            c = __builtin_amdgcn_mfma_f32_16x16x32_bf16(af[kb], f, c, 0, 0, 0);
        }
        cc[tn] = c;
        // pool partial: sum over 4-lane w-groups
        f32x4 t = c;
        #pragma unroll
        for (int r = 0; r < 4; ++r) {
            t[r] += __shfl_xor(t[r], 1);
            t[r] += __shfl_xor(t[r], 2);
        }
        if ((l15 & 3) == 0) {
            int pw = tn * 4 + (l15 >> 2);
            #pragma unroll
            for (int r = 0; r < 4; ++r) sh_pool[wave][q * 4 + r][pw] = t[r];
        }
    }
    __syncthreads();
    if (tid < 128) {
        int b = tid >> 3, pw = tid & 7;
        float s = sh_pool[0][b][pw] + sh_pool[1][b][pw] +
                  sh_pool[2][b][pw] + sh_pool[3][b][pw];
        sh_gate[b][pw] = hsig(s * (1.0f / 16.0f));
    }
    __syncthreads();
    #pragma unroll
    for (int tn = 0; tn < 2; ++tn) {
        int nn = n0 + tn * 16 + l15;
        int pw = tn * 4 + (l15 >> 2);
        #pragma unroll
        for (int r = 0; r < 4; ++r)
            out[(long)(b0 + q * 4 + r) * 16384 + nn] = cc[tn][r] * sh_gate[q * 4 + r][pw];
    }
}

extern "C" void kernel_launch(void* const* d_in, const int* in_sizes, int n_in,
                              void* d_out, int out_size, void* d_ws, size_t ws_size,
                              hipStream_t stream) {
    const float* x      = (const float*)d_in[0];
    const float* W_ih   = (const float*)d_in[1];
    const float* b_ih   = (const float*)d_in[2];
    const float* W_hh   = (const float*)d_in[3];
    const float* b_hh   = (const float*)d_in[4];
    const float* W_gate = (const float*)d_in[5];
    const float* b_gate = (const float*)d_in[6];
    const float* W_map  = (const float*)d_in[7];
    const float* b_map  = (const float*)d_in[8];
    float* out = (float*)d_out;

    const size_t wm_bytes = (size_t)16384 * HID * 2;
    const size_t agg_bytes = (size_t)BATCH * HID * 4;
    const bool pre = ws_size >= wm_bytes + agg_bytes;

    if (pre) {
        short* wm_bf = (short*)d_ws;
        float* agg   = (float*)((char*)d_ws + wm_bytes);

        cvt_kernel<<<(16384 * HID / 4 + 255) / 256, 256, 0, stream>>>(W_map, wm_bf, 16384 * HID / 4);
        rnn_kernel<<<32, 512, 0, stream>>>(x, W_ih, b_ih, W_hh, b_hh,
                                           W_gate, b_gate, agg);
        map_kernel<true><<<4096, 256, 0, stream>>>(agg, W_map, wm_bf, b_map, out);
    } else {
        float* agg = (float*)d_ws;
        rnn_kernel<<<32, 512, 0, stream>>>(x, W_ih, b_ih, W_hh, b_hh,
                                           W_gate, b_gate, agg);
        map_kernel<false><<<4096, 256, 0, stream>>>(agg, W_map, nullptr, b_map, out);
    }
}

// Round 7
// 702.285 us; speedup vs baseline: 1.0953x; 1.0953x over previous
//
#include <hip/hip_runtime.h>
#include <hip/hip_bf16.h>

#define T_SEQ 1024
#define BATCH 512
#define INPUT 64
#define HID   128

typedef __attribute__((ext_vector_type(8))) short bf16x8;
typedef __attribute__((ext_vector_type(4))) short s16x4;
typedef __attribute__((ext_vector_type(4))) float f32x4;
typedef __attribute__((ext_vector_type(2))) unsigned int u32x2;

#define MFMA __builtin_amdgcn_mfma_f32_16x16x32_bf16

__device__ __forceinline__ short f2bf(float f) {
    union { float f; unsigned u; } v; v.f = f;
    unsigned r = (v.u + 0x7FFFu + ((v.u >> 16) & 1u)) >> 16;
    return (short)r;
}

// packed RNE f32x2 -> bf16x2
__device__ __forceinline__ unsigned cvtpk_bf16(float lo, float hi) {
    unsigned r;
    asm("v_cvt_pk_bf16_f32 %0, %1, %2" : "=v"(r) : "v"(lo), "v"(hi));
    return r;
}

// tanh(x) = 1 - 2/(exp(2x)+1); inf-safe
__device__ __forceinline__ float fast_tanh(float s) {
    float e = __expf(2.0f * s);
    return 1.0f - 2.0f * __builtin_amdgcn_rcpf(e + 1.0f);
}

__device__ __forceinline__ float hsig(float v) {
    return __builtin_amdgcn_fmed3f(v * 0.16666666666666666f + 0.5f, 0.0f, 1.0f);
}

// Barrier draining ONLY lgkmcnt (LDS). Global x-prefetch loads stay in flight.
__device__ __forceinline__ void wg_barrier_lds() {
    asm volatile("s_waitcnt lgkmcnt(0)" ::: "memory");
    __builtin_amdgcn_s_barrier();
    asm volatile("" ::: "memory");
}

// ---------------- prep: f32 -> bf16 bulk convert ----------------
__global__ __launch_bounds__(256) void cvt_kernel(const float* __restrict__ in,
                                                  short* __restrict__ out, int n4) {
    int i = blockIdx.x * 256 + threadIdx.x;
    if (i >= n4) return;
    f32x4 v = ((const f32x4*)in)[i];
    s16x4 o;
    #pragma unroll
    for (int j = 0; j < 4; ++j) o[j] = f2bf(v[j]);
    ((s16x4*)out)[i] = o;
}

// ---------------- Stage 1: recurrence (R2 structure, measured 449.8us) ----------------
// 32 blocks x 512 threads. Block: 16 batches.
// TRANSPOSED MFMA: C^T = W * h^T; C^T lane holds 4 consecutive hidden rows ->
// cvt_pk + single ds_write_b64.
// PIPELINE: group A (waves 0-3) owns even t, group B (waves 4-7) odd t; the
// non-owning group runs gate/agg/accx shadow work. 1 barrier per step.
// Step time is a ~1054cyc latency chain (R0-R5: invariant to issue load); x is
// prestaged to bf16 (R5's f32-direct path cost +122cyc/step - reverted).
// Tweak A: critical's h-MFMAs as 8 INDEPENDENT MFMAs + pairwise adds (depth:
// read -> 1 MFMA -> 2 adds -> tanh; was read -> 2 chained MFMAs -> add -> tanh).
template<bool PRE>
__global__ __launch_bounds__(512, 2) void rnn_kernel(
    const float* __restrict__ xf_, const short* __restrict__ xb,
    const float* __restrict__ W_ih, const float* __restrict__ b_ih,
    const float* __restrict__ W_hh, const float* __restrict__ b_hh,
    const float* __restrict__ W_gate, const float* __restrict__ b_gate,
    float* __restrict__ agg_out)
{
    __shared__ __align__(16) short sh[2][16][136];

    const int tid  = threadIdx.x;
    const int wave = tid >> 6, lane = tid & 63;
    const int q = lane >> 4, l15 = lane & 15;
    const int b0 = blockIdx.x * 16;
    const int group = wave >> 2;          // 0: even steps, 1: odd steps
    const int gw = wave & 3;              // hidden rows [32*gw, 32*gw+32)
    const int R0 = 32 * gw, R1 = R0 + 16;

    // ---- one-time: weight A-frags (lane: W[row = Rt + l15][k = 32f + q*8 + j]) ----
    bf16x8 wih[2][2], whh[2][4], wgf[2][4];
    #pragma unroll
    for (int tile = 0; tile < 2; ++tile) {
        const int row = (tile ? R1 : R0) + l15;
        #pragma unroll
        for (int f = 0; f < 2; ++f) {
            const float* p = W_ih + row * INPUT + f * 32 + q * 8;
            bf16x8 v;
            #pragma unroll
            for (int j = 0; j < 8; ++j) v[j] = f2bf(p[j]);
            wih[tile][f] = v;
        }
        #pragma unroll
        for (int f = 0; f < 4; ++f) {
            const float* p = W_hh + row * HID + f * 32 + q * 8;
            bf16x8 v;
            #pragma unroll
            for (int j = 0; j < 8; ++j) v[j] = f2bf(p[j]);
            whh[tile][f] = v;
        }
        #pragma unroll
        for (int f = 0; f < 4; ++f) {
            const float* p = W_gate + row * HID + f * 32 + q * 8;
            bf16x8 v;
            #pragma unroll
            for (int j = 0; j < 8; ++j) v[j] = f2bf(p[j]);
            wgf[tile][f] = v;
        }
    }

    // ---- biases in C^T layout: row = Rt + q*4 + r ----
    f32x4 bias1[2], biasg[2], zero4;
    #pragma unroll
    for (int tile = 0; tile < 2; ++tile) {
        const int rbase = (tile ? R1 : R0) + q * 4;
        #pragma unroll
        for (int r = 0; r < 4; ++r) {
            bias1[tile][r] = b_ih[rbase + r] + b_hh[rbase + r];
            biasg[tile][r] = b_gate[rbase + r];
        }
    }
    #pragma unroll
    for (int r = 0; r < 4; ++r) zero4[r] = 0.0f;

    f32x4 agg0 = zero4, agg1 = zero4;
    f32x4 hpA = zero4, hpB = zero4;       // own h(s) values (f32, C^T layout)
    f32x4 accx0, accx1;                   // x-part for next own step
    bf16x8 xf0, xf1;                      // x B-frags for next own step

    const long lanebase = ((long)(b0 + l15) * T_SEQ) * INPUT + q * 8;
    const short* xb_lane = PRE ? (xb + lanebase) : nullptr;
    const float* xf_lane = PRE ? nullptr : (xf_ + lanebase);

    auto load_x = [&](int tt) {
        if constexpr (PRE) {
            const short* p = xb_lane + (long)tt * INPUT;
            xf0 = *(const bf16x8*)p;
            xf1 = *(const bf16x8*)(p + 32);
        } else {
            const float* p = xf_lane + (long)tt * INPUT;
            f32x4 a0 = *(const f32x4*)p,        a1 = *(const f32x4*)(p + 4);
            f32x4 a2 = *(const f32x4*)(p + 32), a3 = *(const f32x4*)(p + 36);
            #pragma unroll
            for (int j = 0; j < 4; ++j) {
                xf0[j] = f2bf(a0[j]); xf0[4 + j] = f2bf(a1[j]);
                xf1[j] = f2bf(a2[j]); xf1[4 + j] = f2bf(a3[j]);
            }
        }
    };

    // critical interval t: h(t) = tanh(W_hh h(t-1) + accx(t)); write buf[t&1]; prefetch x(t+2)
    auto critical = [&](int t) {
        const int rb = (t & 1) ^ 1, wb = t & 1;
        bf16x8 hf0 = *(const bf16x8*)&sh[rb][l15][q * 8];
        bf16x8 hf1 = *(const bf16x8*)&sh[rb][l15][32 + q * 8];
        bf16x8 hf2 = *(const bf16x8*)&sh[rb][l15][64 + q * 8];
        bf16x8 hf3 = *(const bf16x8*)&sh[rb][l15][96 + q * 8];
        // Tweak A: 8 INDEPENDENT MFMAs (chain depth = 1 MFMA), pairwise adds after.
        f32x4 a0 = MFMA(whh[0][0], hf0, accx0, 0, 0, 0);
        f32x4 a1 = MFMA(whh[1][0], hf0, accx1, 0, 0, 0);
        f32x4 b0v = MFMA(whh[0][1], hf1, zero4, 0, 0, 0);
        f32x4 b1v = MFMA(whh[1][1], hf1, zero4, 0, 0, 0);
        f32x4 c0 = MFMA(whh[0][2], hf2, zero4, 0, 0, 0);
        f32x4 c1 = MFMA(whh[1][2], hf2, zero4, 0, 0, 0);
        f32x4 d0 = MFMA(whh[0][3], hf3, zero4, 0, 0, 0);
        f32x4 d1 = MFMA(whh[1][3], hf3, zero4, 0, 0, 0);
        // prefetch x(t+2) for next shadow's accx (fire & forget; clamped)
        int tt = t + 2; if (tt > T_SEQ - 1) tt = T_SEQ - 1;
        load_x(tt);
        f32x4 s0 = (a0 + b0v) + (c0 + d0);
        f32x4 s1 = (a1 + b1v) + (c1 + d1);
        hpA[0] = fast_tanh(s0[0]);
        hpA[1] = fast_tanh(s0[1]);
        hpA[2] = fast_tanh(s0[2]);
        hpA[3] = fast_tanh(s0[3]);
        hpB[0] = fast_tanh(s1[0]);
        hpB[1] = fast_tanh(s1[1]);
        hpB[2] = fast_tanh(s1[2]);
        hpB[3] = fast_tanh(s1[3]);
        u32x2 p0, p1;
        p0[0] = cvtpk_bf16(hpA[0], hpA[1]); p0[1] = cvtpk_bf16(hpA[2], hpA[3]);
        p1[0] = cvtpk_bf16(hpB[0], hpB[1]); p1[1] = cvtpk_bf16(hpB[2], hpB[3]);
        *(u32x2*)&sh[wb][l15][R0 + q * 4] = p0;
        *(u32x2*)&sh[wb][l15][R1 + q * 4] = p1;
    };

    // shadow interval t: gate(t-1) + agg, then accx(t+1) from prefetched xf
    auto shadow = [&](int t) {
        const int rb = (t & 1) ^ 1;
        bf16x8 gf0 = *(const bf16x8*)&sh[rb][l15][q * 8];
        bf16x8 gf1 = *(const bf16x8*)&sh[rb][l15][32 + q * 8];
        bf16x8 gf2 = *(const bf16x8*)&sh[rb][l15][64 + q * 8];
        bf16x8 gf3 = *(const bf16x8*)&sh[rb][l15][96 + q * 8];
        f32x4 g0 = MFMA(wgf[0][0], gf0, biasg[0], 0, 0, 0);
        f32x4 e0 = MFMA(wgf[0][2], gf2, zero4, 0, 0, 0);
        f32x4 g1 = MFMA(wgf[1][0], gf0, biasg[1], 0, 0, 0);
        f32x4 e1 = MFMA(wgf[1][2], gf2, zero4, 0, 0, 0);
        g0 = MFMA(wgf[0][1], gf1, g0, 0, 0, 0);
        e0 = MFMA(wgf[0][3], gf3, e0, 0, 0, 0);
        g1 = MFMA(wgf[1][1], gf1, g1, 0, 0, 0);
        e1 = MFMA(wgf[1][3], gf3, e1, 0, 0, 0);
        accx0 = MFMA(wih[0][0], xf0, bias1[0], 0, 0, 0);
        accx1 = MFMA(wih[1][0], xf0, bias1[1], 0, 0, 0);
        accx0 = MFMA(wih[0][1], xf1, accx0, 0, 0, 0);
        accx1 = MFMA(wih[1][1], xf1, accx1, 0, 0, 0);
        #pragma unroll
        for (int r = 0; r < 4; ++r) {
            agg0[r] += hpA[r] * hsig(g0[r] + e0[r]);
            agg1[r] += hpB[r] * hsig(g1[r] + e1[r]);
        }
    };

    // ---- prologue ----
    load_x(group);                         // x(0) for A, x(1) for B
    accx0 = MFMA(wih[0][0], xf0, bias1[0], 0, 0, 0);
    accx1 = MFMA(wih[1][0], xf0, bias1[1], 0, 0, 0);
    accx0 = MFMA(wih[0][1], xf1, accx0, 0, 0, 0);
    accx1 = MFMA(wih[1][1], xf1, accx1, 0, 0, 0);
    if (group == 0) {
        // h(0) = tanh(accx(0)); write buf[0]
        hpA[0] = fast_tanh(accx0[0]); hpA[1] = fast_tanh(accx0[1]);
        hpA[2] = fast_tanh(accx0[2]); hpA[3] = fast_tanh(accx0[3]);
        hpB[0] = fast_tanh(accx1[0]); hpB[1] = fast_tanh(accx1[1]);
        hpB[2] = fast_tanh(accx1[2]); hpB[3] = fast_tanh(accx1[3]);
        u32x2 p0, p1;
        p0[0] = cvtpk_bf16(hpA[0], hpA[1]); p0[1] = cvtpk_bf16(hpA[2], hpA[3]);
        p1[0] = cvtpk_bf16(hpB[0], hpB[1]); p1[1] = cvtpk_bf16(hpB[2], hpB[3]);
        *(u32x2*)&sh[0][l15][R0 + q * 4] = p0;
        *(u32x2*)&sh[0][l15][R1 + q * 4] = p1;
        load_x(2);                         // for shadow(1) -> accx(2)
    }
    wg_barrier_lds();

    // ---- main loop: t = 1 .. 1022 in pairs, tail t = 1023 ----
    if (group == 0) {
        for (int i = 0; i < 511; ++i) {
            shadow(2 * i + 1);   wg_barrier_lds();
            critical(2 * i + 2); wg_barrier_lds();
        }
        shadow(1023); wg_barrier_lds();
    } else {
        for (int i = 0; i < 511; ++i) {
            critical(2 * i + 1); wg_barrier_lds();
            shadow(2 * i + 2);   wg_barrier_lds();
        }
        critical(1023); wg_barrier_lds();
    }

    // ---- epilogue ----
    // B owns h(1023) (in sh[1]): compute its last gate term.
    if (group == 1) {
        bf16x8 gf0 = *(const bf16x8*)&sh[1][l15][q * 8];
        bf16x8 gf1 = *(const bf16x8*)&sh[1][l15][32 + q * 8];
        bf16x8 gf2 = *(const bf16x8*)&sh[1][l15][64 + q * 8];
        bf16x8 gf3 = *(const bf16x8*)&sh[1][l15][96 + q * 8];
        f32x4 g0 = MFMA(wgf[0][0], gf0, biasg[0], 0, 0, 0);
        f32x4 e0 = MFMA(wgf[0][2], gf2, zero4, 0, 0, 0);
        f32x4 g1 = MFMA(wgf[1][0], gf0, biasg[1], 0, 0, 0);
        f32x4 e1 = MFMA(wgf[1][2], gf2, zero4, 0, 0, 0);
        g0 = MFMA(wgf[0][1], gf1, g0, 0, 0, 0);
        e0 = MFMA(wgf[0][3], gf3, e0, 0, 0, 0);
        g1 = MFMA(wgf[1][1], gf1, g1, 0, 0, 0);
        e1 = MFMA(wgf[1][3], gf3, e1, 0, 0, 0);
        #pragma unroll
        for (int r = 0; r < 4; ++r) {
            agg0[r] += hpA[r] * hsig(g0[r] + e0[r]);
            agg1[r] += hpB[r] * hsig(g1[r] + e1[r]);
        }
    }
    wg_barrier_lds();                      // B's gf reads done before A overwrites LDS

    float* aggf = (float*)&sh[0][0][0];    // reuse as float[16][128]
    if (group == 0) {
        *(f32x4*)&aggf[l15 * HID + R0 + q * 4] = agg0;
        *(f32x4*)&aggf[l15 * HID + R1 + q * 4] = agg1;
    }
    wg_barrier_lds();
    if (group == 1) {
        const float s = 1.0f / (float)T_SEQ;
        f32x4 t0 = *(const f32x4*)&aggf[l15 * HID + R0 + q * 4];
        f32x4 t1 = *(const f32x4*)&aggf[l15 * HID + R1 + q * 4];
        #pragma unroll
        for (int r = 0; r < 4; ++r) { t0[r] = (t0[r] + agg0[r]) * s; t1[r] = (t1[r] + agg1[r]) * s; }
        *(f32x4*)&agg_out[(long)(b0 + l15) * HID + R0 + q * 4] = t0;
        *(f32x4*)&agg_out[(long)(b0 + l15) * HID + R1 + q * 4] = t1;
    }
}

// ---------------- Stage 2: mapped = agg @ W_map^T + b_map, FUSED pool+gate ----------------
// Block (mb, nb): batches mb*16..+16, cols nb*128..+128. col = c*1024 + h*32 + w
// with c = nb>>3, h = 4*(nb&7) + wave, w = tn*16 + l15: the block covers exactly
// one pool-window row -> 4x4 pooling is block-local. shfl over 4-lane w-groups,
// per-wave LDS partials over h, gate = hsig(sum/16), multiply before the store.
template<bool PRE>
__global__ __launch_bounds__(256) void map_kernel(
    const float* __restrict__ agg, const float* __restrict__ Wf,
    const short* __restrict__ Wb, const float* __restrict__ b_map,
    float* __restrict__ out)
{
    __shared__ float sh_pool[4][16][8];
    __shared__ float sh_gate[16][8];

    const int tid  = threadIdx.x;
    const int wave = tid >> 6, lane = tid & 63;
    const int q = lane >> 4, l15 = lane & 15;
    const int mb = blockIdx.x & 31;
    const int nb = blockIdx.x >> 5;
    const int b0 = mb * 16;
    const int n0 = nb * 128 + wave * 32;

    bf16x8 af[4];
    #pragma unroll
    for (int kb = 0; kb < 4; ++kb) {
        const float* p = agg + (b0 + l15) * HID + kb * 32 + q * 8;
        bf16x8 f;
        #pragma unroll
        for (int j = 0; j < 8; ++j) f[j] = f2bf(p[j]);
        af[kb] = f;
    }
    f32x4 cc[2];
    #pragma unroll
    for (int tn = 0; tn < 2; ++tn) {
        int nn = n0 + tn * 16 + l15;
        float bias = b_map[nn];
        f32x4 c;
        #pragma unroll
        for (int r = 0; r < 4; ++r) c[r] = bias;
        #pragma unroll
        for (int kb = 0; kb < 4; ++kb) {
            bf16x8 f;
            if (PRE) {
                f = *(const bf16x8*)(Wb + (long)nn * HID + kb * 32 + q * 8);
            } else {
                const float* p = Wf + (long)nn * HID + kb * 32 + q * 8;
                #pragma unroll
                for (int j = 0; j < 8; ++j) f[j] = f2bf(p[j]);
            }
            c = __builtin_amdgcn_mfma_f32_16x16x32_bf16(af[kb], f, c, 0, 0, 0);
        }
        cc[tn] = c;
        // pool partial: sum over 4-lane w-groups
        f32x4 t = c;
        #pragma unroll
        for (int r = 0; r < 4; ++r) {
            t[r] += __shfl_xor(t[r], 1);
            t[r] += __shfl_xor(t[r], 2);
        }
        if ((l15 & 3) == 0) {
            int pw = tn * 4 + (l15 >> 2);
            #pragma unroll
            for (int r = 0; r < 4; ++r) sh_pool[wave][q * 4 + r][pw] = t[r];
        }
    }
    __syncthreads();
    if (tid < 128) {
        int b = tid >> 3, pw = tid & 7;
        float s = sh_pool[0][b][pw] + sh_pool[1][b][pw] +
                  sh_pool[2][b][pw] + sh_pool[3][b][pw];
        sh_gate[b][pw] = hsig(s * (1.0f / 16.0f));
    }
    __syncthreads();
    #pragma unroll
    for (int tn = 0; tn < 2; ++tn) {
        int nn = n0 + tn * 16 + l15;
        int pw = tn * 4 + (l15 >> 2);
        #pragma unroll
        for (int r = 0; r < 4; ++r)
            out[(long)(b0 + q * 4 + r) * 16384 + nn] = cc[tn][r] * sh_gate[q * 4 + r][pw];
    }
}

extern "C" void kernel_launch(void* const* d_in, const int* in_sizes, int n_in,
                              void* d_out, int out_size, void* d_ws, size_t ws_size,
                              hipStream_t stream) {
    const float* x      = (const float*)d_in[0];
    const float* W_ih   = (const float*)d_in[1];
    const float* b_ih   = (const float*)d_in[2];
    const float* W_hh   = (const float*)d_in[3];
    const float* b_hh   = (const float*)d_in[4];
    const float* W_gate = (const float*)d_in[5];
    const float* b_gate = (const float*)d_in[6];
    const float* W_map  = (const float*)d_in[7];
    const float* b_map  = (const float*)d_in[8];
    float* out = (float*)d_out;

    const size_t xb_bytes = (size_t)BATCH * T_SEQ * INPUT * 2;
    const size_t wm_bytes = (size_t)16384 * HID * 2;
    const size_t agg_bytes = (size_t)BATCH * HID * 4;
    const bool pre = ws_size >= xb_bytes + wm_bytes + agg_bytes;

    if (pre) {
        short* x_bf  = (short*)d_ws;
        short* wm_bf = (short*)((char*)d_ws + xb_bytes);
        float* agg   = (float*)((char*)d_ws + xb_bytes + wm_bytes);

        cvt_kernel<<<(BATCH * T_SEQ * INPUT / 4 + 255) / 256, 256, 0, stream>>>(x, x_bf, BATCH * T_SEQ * INPUT / 4);
        cvt_kernel<<<(16384 * HID / 4 + 255) / 256, 256, 0, stream>>>(W_map, wm_bf, 16384 * HID / 4);
        rnn_kernel<true><<<32, 512, 0, stream>>>(x, x_bf, W_ih, b_ih, W_hh, b_hh,
                                                 W_gate, b_gate, agg);
        map_kernel<true><<<4096, 256, 0, stream>>>(agg, W_map, wm_bf, b_map, out);
    } else {
        float* agg = (float*)d_ws;
        rnn_kernel<false><<<32, 512, 0, stream>>>(x, nullptr, W_ih, b_ih, W_hh, b_hh,
                                                  W_gate, b_gate, agg);
        map_kernel<false><<<4096, 256, 0, stream>>>(agg, W_map, nullptr, b_map, out);
    }
}